// Round 1
// baseline (1927.875 us; speedup 1.0000x reference)
//
#include <hip/hip_runtime.h>
#include <math.h>
#include <float.h>

#define N_NODES 20000
#define N_EDGES 320000
#define DIM 64
#define HD 256
#define NGRAPH 64
#define NLAYER 3
#define BN_EPS 1e-5f

// ---------------- CSR construction ----------------
__global__ void count_kernel(const int* __restrict__ ei, int* __restrict__ cnt) {
    int e = blockIdx.x * blockDim.x + threadIdx.x;
    if (e < N_EDGES) atomicAdd(&cnt[ei[N_EDGES + e]], 1);
}

__global__ void scan_kernel(const int* __restrict__ cnt, int* __restrict__ rowptr) {
    __shared__ int sh[256];
    int t = threadIdx.x;
    const int CH = (N_NODES + 255) / 256;  // 79
    int base = t * CH;
    int s = 0;
    for (int i = 0; i < CH; i++) { int idx = base + i; if (idx < N_NODES) s += cnt[idx]; }
    sh[t] = s;
    __syncthreads();
    // inclusive Hillis-Steele scan
    for (int off = 1; off < 256; off <<= 1) {
        int v = sh[t];
        int add = (t >= off) ? sh[t - off] : 0;
        __syncthreads();
        sh[t] = v + add;
        __syncthreads();
    }
    int run = sh[t] - s;  // exclusive prefix for this chunk
    for (int i = 0; i < CH; i++) {
        int idx = base + i;
        if (idx < N_NODES) { rowptr[idx] = run; run += cnt[idx]; }
    }
    if (t == 255) rowptr[N_NODES] = sh[255];
}

__global__ void fill_kernel(const int* __restrict__ ei, const int* __restrict__ rowptr,
                            int* __restrict__ cur, int* __restrict__ eidx,
                            int* __restrict__ esrc) {
    int e = blockIdx.x * blockDim.x + threadIdx.x;
    if (e < N_EDGES) {
        int dst = ei[N_EDGES + e];
        int pos = atomicAdd(&cur[dst], 1);
        int slot = rowptr[dst] + pos;
        eidx[slot] = e;
        esrc[slot] = ei[e];
    }
}

// ---------------- node linear: q,k,v,skip ----------------
__global__ __launch_bounds__(256) void node_lin_kernel(
    const float* __restrict__ x,
    const float* __restrict__ Wq, const float* __restrict__ bq,
    const float* __restrict__ Wk, const float* __restrict__ bk,
    const float* __restrict__ Wv, const float* __restrict__ bv,
    const float* __restrict__ Ws, const float* __restrict__ bs,
    float* __restrict__ oq, float* __restrict__ ok,
    float* __restrict__ ov, float* __restrict__ os) {
    __shared__ float Wl[64 * 256];   // 64 KB
    __shared__ float xl[64 * 64];    // 16 KB
    const float* W; const float* b; float* out;
    switch (blockIdx.y) {
        case 0:  W = Wq; b = bq; out = oq; break;
        case 1:  W = Wk; b = bk; out = ok; break;
        case 2:  W = Wv; b = bv; out = ov; break;
        default: W = Ws; b = bs; out = os; break;
    }
    int t = threadIdx.x;
    for (int i = t; i < 64 * 256; i += 256) Wl[i] = W[i];
    int n0 = blockIdx.x * 64;
    for (int i = t; i < 64 * 64; i += 256) {
        int n = n0 + (i >> 6);
        xl[i] = (n < N_NODES) ? x[(size_t)n0 * 64 + i] : 0.f;
    }
    __syncthreads();
    float bc = b[t];
    for (int ng = 0; ng < 64; ng += 4) {
        float a0 = bc, a1 = bc, a2 = bc, a3 = bc;
#pragma unroll 8
        for (int k = 0; k < 64; k++) {
            float w = Wl[k * 256 + t];
            a0 += xl[(ng + 0) * 64 + k] * w;
            a1 += xl[(ng + 1) * 64 + k] * w;
            a2 += xl[(ng + 2) * 64 + k] * w;
            a3 += xl[(ng + 3) * 64 + k] * w;
        }
        int n = n0 + ng;
        if (n + 0 < N_NODES) out[(size_t)(n + 0) * 256 + t] = a0;
        if (n + 1 < N_NODES) out[(size_t)(n + 1) * 256 + t] = a1;
        if (n + 2 < N_NODES) out[(size_t)(n + 2) * 256 + t] = a2;
        if (n + 3 < N_NODES) out[(size_t)(n + 3) * 256 + t] = a3;
    }
}

// ---------------- fused attention (per dst node) ----------------
// block = 256 threads = 4 waves; wave w == head w, lane == channel within head.
__global__ __launch_bounds__(256) void attn_kernel(
    const float* __restrict__ edge_attr,
    const float* __restrict__ We,     // [64,256] layer slice
    const int* __restrict__ rowptr, const int* __restrict__ eidx,
    const int* __restrict__ esrc,
    const float* __restrict__ qb, const float* __restrict__ kb,
    const float* __restrict__ vb, const float* __restrict__ sb,
    float* __restrict__ hb) {
    int c = threadIdx.x;
    float wcol[64];
#pragma unroll
    for (int k = 0; k < 64; k++) wcol[k] = We[k * 256 + c];

    for (int n = blockIdx.x; n < N_NODES; n += gridDim.x) {
        float qc = qb[(size_t)n * 256 + c];
        float sc = sb[(size_t)n * 256 + c];
        int j0 = rowptr[n], j1 = rowptr[n + 1];
        float m = -FLT_MAX, l = 0.f, acc = 0.f;
        for (int j = j0; j < j1; j++) {
            int eid = __builtin_amdgcn_readfirstlane(eidx[j]);
            int src = __builtin_amdgcn_readfirstlane(esrc[j]);
            const float* ea = edge_attr + (size_t)eid * 64;
            float ec = 0.f;
#pragma unroll
            for (int k = 0; k < 64; k++) ec += ea[k] * wcol[k];
            float kc = kb[(size_t)src * 256 + c] + ec;
            float tt = qc * kc;
#pragma unroll
            for (int off = 32; off; off >>= 1) tt += __shfl_xor(tt, off);
            float logit = tt * 0.125f;           // 1/sqrt(64)
            float mn = fmaxf(m, logit);
            float scale = expf(m - mn);
            float p = expf(logit - mn);
            l = l * scale + p;
            float vc = vb[(size_t)src * 256 + c] + ec;
            acc = acc * scale + p * vc;
            m = mn;
        }
        float o = (l > 0.f) ? acc / l : 0.f;
        hb[(size_t)n * 256 + c] = o + sc;
    }
}

// ---------------- batch-norm stats ----------------
__global__ void bn_stat_kernel(const float* __restrict__ h, float* __restrict__ stats) {
    int c = threadIdx.x;
    float s = 0.f, s2 = 0.f;
    for (int r = blockIdx.x; r < N_NODES; r += gridDim.x) {
        float v = h[(size_t)r * 256 + c];
        s += v; s2 += v * v;
    }
    atomicAdd(&stats[c], s);
    atomicAdd(&stats[256 + c], s2);
}

// fold BN affine into Wt / bias
__global__ void bn_fold_kernel(const float* __restrict__ stats,
                               const float* __restrict__ gamma, const float* __restrict__ beta,
                               const float* __restrict__ Wt, const float* __restrict__ bt,
                               float* __restrict__ Wtp, float* __restrict__ biasp) {
    __shared__ float bsh[256];
    int c = threadIdx.x;
    float mean = stats[c] * (1.f / N_NODES);
    float var = stats[256 + c] * (1.f / N_NODES) - mean * mean;
    float a = rsqrtf(var + BN_EPS) * gamma[c];
    float bb = beta[c] - mean * a;
    bsh[c] = bb;
    for (int d = 0; d < 64; d++) Wtp[c * 64 + d] = a * Wt[c * 64 + d];
    __syncthreads();
    if (c < 64) {
        float acc = bt[c];
        for (int k = 0; k < 256; k++) acc += bsh[k] * Wt[k * 64 + c];
        biasp[c] = acc;
    }
}

// x_next = relu(h_bn @ Wt + bt)   (BN folded into Wtp/biasp)
__global__ __launch_bounds__(256) void xform_kernel(
    const float* __restrict__ h, const float* __restrict__ Wtp,
    const float* __restrict__ biasp, float* __restrict__ xo) {
    __shared__ float Wl[256 * 64];  // 64 KB
    int t = threadIdx.x;
    for (int i = t; i < 256 * 64; i += 256) Wl[i] = Wtp[i];
    __syncthreads();
    int d = t & 63, ln = t >> 6;
    float bp = biasp[d];
    const int ngroups = (N_NODES + 3) / 4;
    for (int g = blockIdx.x; g < ngroups; g += gridDim.x) {
        int n = g * 4 + ln;
        if (n < N_NODES) {
            float acc = bp;
#pragma unroll 4
            for (int k = 0; k < 256; k++) acc += h[(size_t)n * 256 + k] * Wl[k * 64 + d];
            xo[(size_t)n * 64 + d] = fmaxf(acc, 0.f);
        }
    }
}

// ---------------- graph pooling (batch is contiguous ranges) ----------------
__global__ void pool_kernel(const float* __restrict__ x, float* __restrict__ rep) {
    int g = blockIdx.x, d = threadIdx.x;
    int start = (N_NODES * g + 63) >> 6;
    int end = (N_NODES * (g + 1) + 63) >> 6;
    float mx = -FLT_MAX, sm = 0.f;
    for (int r = start; r < end; r++) {
        float v = x[(size_t)r * 64 + d];
        mx = fmaxf(mx, v);
        sm += v;
    }
    rep[g * 128 + d] += mx;
    rep[g * 128 + 64 + d] += sm / (float)(end - start);
}

// ---------------- MLP head ----------------
__global__ void head1_kernel(const float* __restrict__ rep, const float* __restrict__ W1,
                             const float* __restrict__ b1, float* __restrict__ o1) {
    int g = blockIdx.x, c = threadIdx.x;
    float acc = b1[c];
    for (int k = 0; k < 128; k++) acc += rep[g * 128 + k] * W1[k * 256 + c];
    o1[g * 256 + c] = fmaxf(acc, 0.f);
}
__global__ void head2_kernel(const float* __restrict__ o1, const float* __restrict__ W2,
                             const float* __restrict__ b2, float* __restrict__ o2) {
    int g = blockIdx.x, c = threadIdx.x;
    float acc = b2[c];
    for (int k = 0; k < 256; k++) acc += o1[g * 256 + k] * W2[k * 128 + c];
    o2[g * 128 + c] = fmaxf(acc, 0.f);
}
__global__ void head3_kernel(const float* __restrict__ o2, const float* __restrict__ W3,
                             const float* __restrict__ b3, float* __restrict__ out) {
    int g = threadIdx.x;
    float acc = b3[0];
    for (int k = 0; k < 128; k++) acc += o2[g * 128 + k] * W3[k];
    out[g] = acc;
}

extern "C" void kernel_launch(void* const* d_in, const int* in_sizes, int n_in,
                              void* d_out, int out_size, void* d_ws, size_t ws_size,
                              hipStream_t stream) {
    const float* x         = (const float*)d_in[0];
    const float* edge_attr = (const float*)d_in[1];
    const int*   ei        = (const int*)d_in[2];
    const float* Wq  = (const float*)d_in[4];
    const float* bq  = (const float*)d_in[5];
    const float* Wk  = (const float*)d_in[6];
    const float* bk  = (const float*)d_in[7];
    const float* Wv  = (const float*)d_in[8];
    const float* bv  = (const float*)d_in[9];
    const float* We  = (const float*)d_in[10];
    const float* Wsk = (const float*)d_in[11];
    const float* bsk = (const float*)d_in[12];
    const float* gam = (const float*)d_in[13];
    const float* bet = (const float*)d_in[14];
    const float* Wt  = (const float*)d_in[15];
    const float* bt  = (const float*)d_in[16];
    const float* W1  = (const float*)d_in[17];
    const float* b1  = (const float*)d_in[18];
    const float* W2  = (const float*)d_in[19];
    const float* b2  = (const float*)d_in[20];
    const float* W3  = (const float*)d_in[21];
    const float* b3  = (const float*)d_in[22];
    float* out = (float*)d_out;

    char* ws = (char*)d_ws;
    size_t off = 0;
    auto alloc = [&](size_t bytes) -> char* {
        char* p = ws + off;
        off += (bytes + 255) & ~(size_t)255;
        return p;
    };
    int*   rowptr = (int*)alloc((N_NODES + 1) * sizeof(int));
    int*   cur    = (int*)alloc(N_NODES * sizeof(int));
    int*   eidx   = (int*)alloc(N_EDGES * sizeof(int));
    int*   esrc   = (int*)alloc(N_EDGES * sizeof(int));
    float* qb     = (float*)alloc((size_t)N_NODES * 256 * sizeof(float));
    float* kb     = (float*)alloc((size_t)N_NODES * 256 * sizeof(float));
    float* vb     = (float*)alloc((size_t)N_NODES * 256 * sizeof(float));
    float* sbv    = (float*)alloc((size_t)N_NODES * 256 * sizeof(float));
    float* hb     = (float*)alloc((size_t)N_NODES * 256 * sizeof(float));
    float* xb     = (float*)alloc((size_t)N_NODES * 64 * sizeof(float));
    float* stats  = (float*)alloc(512 * sizeof(float));
    float* Wtp    = (float*)alloc(256 * 64 * sizeof(float));
    float* biasp  = (float*)alloc(64 * sizeof(float));
    float* rep    = (float*)alloc(64 * 128 * sizeof(float));
    float* o1     = (float*)alloc(64 * 256 * sizeof(float));
    float* o2     = (float*)alloc(64 * 128 * sizeof(float));

    // CSR build
    hipMemsetAsync(cur, 0, N_NODES * sizeof(int), stream);
    count_kernel<<<(N_EDGES + 255) / 256, 256, 0, stream>>>(ei, cur);
    scan_kernel<<<1, 256, 0, stream>>>(cur, rowptr);
    hipMemsetAsync(cur, 0, N_NODES * sizeof(int), stream);
    fill_kernel<<<(N_EDGES + 255) / 256, 256, 0, stream>>>(ei, rowptr, cur, eidx, esrc);

    hipMemsetAsync(rep, 0, 64 * 128 * sizeof(float), stream);

    const float* xcur = x;
    for (int i = 0; i < NLAYER; i++) {
        node_lin_kernel<<<dim3((N_NODES + 63) / 64, 4), 256, 0, stream>>>(
            xcur,
            Wq + i * 16384, bq + i * 256,
            Wk + i * 16384, bk + i * 256,
            Wv + i * 16384, bv + i * 256,
            Wsk + i * 16384, bsk + i * 256,
            qb, kb, vb, sbv);
        attn_kernel<<<1280, 256, 0, stream>>>(
            edge_attr, We + i * 16384, rowptr, eidx, esrc, qb, kb, vb, sbv, hb);
        hipMemsetAsync(stats, 0, 512 * sizeof(float), stream);
        bn_stat_kernel<<<256, 256, 0, stream>>>(hb, stats);
        bn_fold_kernel<<<1, 256, 0, stream>>>(stats, gam + i * 256, bet + i * 256,
                                              Wt + i * 16384, bt + i * 64, Wtp, biasp);
        xform_kernel<<<2048, 256, 0, stream>>>(hb, Wtp, biasp, xb);
        pool_kernel<<<64, 64, 0, stream>>>(xb, rep);
        xcur = xb;
    }

    head1_kernel<<<64, 256, 0, stream>>>(rep, W1, b1, o1);
    head2_kernel<<<64, 128, 0, stream>>>(o1, W2, b2, o2);
    head3_kernel<<<1, 64, 0, stream>>>(o2, W3, b3, out);
}

// Round 2
// 1493.692 us; speedup vs baseline: 1.2907x; 1.2907x over previous
//
#include <hip/hip_runtime.h>
#include <math.h>
#include <float.h>

#define N_NODES 20000
#define N_EDGES 320000
#define DIM 64
#define HD 256
#define NGRAPH 64
#define NLAYER 3
#define BN_EPS 1e-5f

// ---------------- CSR construction ----------------
__global__ void count_kernel(const int* __restrict__ ei, int* __restrict__ cnt) {
    int e = blockIdx.x * blockDim.x + threadIdx.x;
    if (e < N_EDGES) atomicAdd(&cnt[ei[N_EDGES + e]], 1);
}

__global__ void scan_kernel(const int* __restrict__ cnt, int* __restrict__ rowptr) {
    __shared__ int sh[256];
    int t = threadIdx.x;
    const int CH = (N_NODES + 255) / 256;  // 79
    int base = t * CH;
    int s = 0;
    for (int i = 0; i < CH; i++) { int idx = base + i; if (idx < N_NODES) s += cnt[idx]; }
    sh[t] = s;
    __syncthreads();
    for (int off = 1; off < 256; off <<= 1) {
        int v = sh[t];
        int add = (t >= off) ? sh[t - off] : 0;
        __syncthreads();
        sh[t] = v + add;
        __syncthreads();
    }
    int run = sh[t] - s;
    for (int i = 0; i < CH; i++) {
        int idx = base + i;
        if (idx < N_NODES) { rowptr[idx] = run; run += cnt[idx]; }
    }
    if (t == 255) rowptr[N_NODES] = sh[255];
}

__global__ void fill_kernel(const int* __restrict__ ei, const int* __restrict__ rowptr,
                            int* __restrict__ cur, int2* __restrict__ epair) {
    int e = blockIdx.x * blockDim.x + threadIdx.x;
    if (e < N_EDGES) {
        int dst = ei[N_EDGES + e];
        int pos = atomicAdd(&cur[dst], 1);
        epair[rowptr[dst] + pos] = make_int2(e, ei[e]);
    }
}

// ---------------- fold We into Wq:  Wu[j,h,d] = sum_c Wq[j,h,c]*We[d,h,c] ----------------
__global__ void wu_kernel(const float* __restrict__ Wq, const float* __restrict__ bq,
                          const float* __restrict__ We,
                          float* __restrict__ Wu, float* __restrict__ bu) {
    int j = blockIdx.x, layer = blockIdx.y;
    int t = threadIdx.x, h = t >> 6, d = t & 63;
    const float* Wql = Wq + layer * 16384;
    const float* Wel = We + layer * 16384;
    float acc = 0.f;
    for (int c = 0; c < 64; c++)
        acc += Wql[j * 256 + h * 64 + c] * Wel[d * 256 + h * 64 + c];
    Wu[layer * 16384 + j * 256 + h * 64 + d] = acc;
    if (j == 0) {
        const float* bql = bq + layer * 256;
        float ab = 0.f;
        for (int c = 0; c < 64; c++) ab += bql[h * 64 + c] * Wel[d * 256 + h * 64 + c];
        bu[layer * 256 + h * 64 + d] = ab;
    }
}

// ---------------- node linear: q, k/v interleaved, skip, u ----------------
__global__ __launch_bounds__(256) void node_lin_kernel(
    const float* __restrict__ x,
    const float* __restrict__ Wq, const float* __restrict__ bq,
    const float* __restrict__ Wk, const float* __restrict__ bk,
    const float* __restrict__ Wv, const float* __restrict__ bv,
    const float* __restrict__ Ws, const float* __restrict__ bs,
    const float* __restrict__ Wu, const float* __restrict__ bu,
    float* __restrict__ oq, float* __restrict__ okv,
    float* __restrict__ os, float* __restrict__ ou) {
    __shared__ float Wl[64 * 256];   // 64 KB
    __shared__ float xl[64 * 64];    // 16 KB
    const float* W; const float* b; float* out; int mult, offo;
    switch (blockIdx.y) {
        case 0:  W = Wq; b = bq; out = oq;  mult = 1; offo = 0; break;
        case 1:  W = Wk; b = bk; out = okv; mult = 2; offo = 0; break;
        case 2:  W = Wv; b = bv; out = okv; mult = 2; offo = 1; break;
        case 3:  W = Ws; b = bs; out = os;  mult = 1; offo = 0; break;
        default: W = Wu; b = bu; out = ou;  mult = 1; offo = 0; break;
    }
    int t = threadIdx.x;
    for (int i = t; i < 64 * 256; i += 256) Wl[i] = W[i];
    int n0 = blockIdx.x * 64;
    for (int i = t; i < 64 * 64; i += 256) {
        int n = n0 + (i >> 6);
        xl[i] = (n < N_NODES) ? x[(size_t)n0 * 64 + i] : 0.f;
    }
    __syncthreads();
    float bc = b[t];
    for (int ng = 0; ng < 64; ng += 4) {
        float a0 = bc, a1 = bc, a2 = bc, a3 = bc;
#pragma unroll 8
        for (int k = 0; k < 64; k++) {
            float w = Wl[k * 256 + t];
            a0 += xl[(ng + 0) * 64 + k] * w;
            a1 += xl[(ng + 1) * 64 + k] * w;
            a2 += xl[(ng + 2) * 64 + k] * w;
            a3 += xl[(ng + 3) * 64 + k] * w;
        }
        int n = n0 + ng;
        if (n + 0 < N_NODES) out[((size_t)(n + 0) * 256 + t) * mult + offo] = a0;
        if (n + 1 < N_NODES) out[((size_t)(n + 1) * 256 + t) * mult + offo] = a1;
        if (n + 2 < N_NODES) out[((size_t)(n + 2) * 256 + t) * mult + offo] = a2;
        if (n + 3 < N_NODES) out[((size_t)(n + 3) * 256 + t) * mult + offo] = a3;
    }
}

// ---------------- fused attention: block = 4 waves, all same head; wave = one dst node ----
__global__ __launch_bounds__(256) void attn2_kernel(
    const float* __restrict__ edge_attr,
    const float* __restrict__ We,     // layer slice [64][256]
    const int* __restrict__ rowptr, const int2* __restrict__ epair,
    const float* __restrict__ qb, const float* __restrict__ kvb,
    const float* __restrict__ ub, const float* __restrict__ sb,
    float* __restrict__ hb, float* __restrict__ stats) {
    const int h = blockIdx.y;
    const int t = threadIdx.x;
    const int wid = t >> 6, lane = t & 63;
    __shared__ float WeL[64 * 64];       // We[:, h*64:(h+1)*64]  16 KB
    __shared__ float shr[4][64];
    __shared__ float bnsh[2][4][64];
    for (int i = t; i < 4096; i += 256) {
        int d = i >> 6, c = i & 63;
        WeL[i] = We[d * 256 + h * 64 + c];
    }
    __syncthreads();
    float bns = 0.f, bns2 = 0.f;
    for (int n = blockIdx.x * 4 + wid; n < N_NODES; n += gridDim.x * 4) {
        float qc = qb[(size_t)n * 256 + h * 64 + lane];
        float uc = ub[(size_t)n * 256 + h * 64 + lane];
        int j0 = rowptr[n], j1 = rowptr[n + 1];
        float m = -FLT_MAX, l = 0.f, acc = 0.f, racc = 0.f;
        for (int j = j0; j < j1; j++) {
            int2 ep = epair[j];
            int eid = __builtin_amdgcn_readfirstlane(ep.x);
            int src = __builtin_amdgcn_readfirstlane(ep.y);
            float2 kv = *(const float2*)(kvb + (size_t)src * 512 + h * 128 + lane * 2);
            float eac = edge_attr[(size_t)eid * 64 + lane];
            float t0 = qc * kv.x + uc * eac;
#pragma unroll
            for (int off = 32; off; off >>= 1) t0 += __shfl_xor(t0, off);
            float logit = t0 * 0.125f;            // / sqrt(64)
            float mn = fmaxf(m, logit);
            float sca = __expf(m - mn);
            float p   = __expf(logit - mn);
            l    = l * sca + p;
            acc  = acc * sca + p * kv.y;
            racc = racc * sca + p * eac;
            m = mn;
        }
        float inv = (l > 0.f) ? 1.f / l : 0.f;
        acc *= inv; racc *= inv;
        shr[wid][lane] = racc;
        float msg = 0.f;
#pragma unroll 8
        for (int d = 0; d < 64; d++) msg += shr[wid][d] * WeL[d * 64 + lane];
        float hv = acc + msg + sb[(size_t)n * 256 + h * 64 + lane];
        hb[(size_t)n * 256 + h * 64 + lane] = hv;
        bns += hv; bns2 += hv * hv;
    }
    bnsh[0][wid][lane] = bns;
    bnsh[1][wid][lane] = bns2;
    __syncthreads();
    if (wid == 0) {
        float a = bnsh[0][0][lane] + bnsh[0][1][lane] + bnsh[0][2][lane] + bnsh[0][3][lane];
        float b = bnsh[1][0][lane] + bnsh[1][1][lane] + bnsh[1][2][lane] + bnsh[1][3][lane];
        atomicAdd(&stats[h * 64 + lane], a);
        atomicAdd(&stats[256 + h * 64 + lane], b);
    }
}

// ---------------- fold BN affine into Wt / bias ----------------
__global__ void bn_fold_kernel(const float* __restrict__ stats,
                               const float* __restrict__ gamma, const float* __restrict__ beta,
                               const float* __restrict__ Wt, const float* __restrict__ bt,
                               float* __restrict__ Wtp, float* __restrict__ biasp) {
    __shared__ float bsh[256];
    int c = threadIdx.x;
    float mean = stats[c] * (1.f / N_NODES);
    float var = stats[256 + c] * (1.f / N_NODES) - mean * mean;
    float a = rsqrtf(var + BN_EPS) * gamma[c];
    float bb = beta[c] - mean * a;
    bsh[c] = bb;
    for (int d = 0; d < 64; d++) Wtp[c * 64 + d] = a * Wt[c * 64 + d];
    __syncthreads();
    if (c < 64) {
        float acc = bt[c];
        for (int k = 0; k < 256; k++) acc += bsh[k] * Wt[k * 64 + c];
        biasp[c] = acc;
    }
}

// x_next = relu(h_bn @ Wt + bt)  (BN folded into Wtp/biasp)
__global__ __launch_bounds__(256) void xform_kernel(
    const float* __restrict__ h, const float* __restrict__ Wtp,
    const float* __restrict__ biasp, float* __restrict__ xo) {
    __shared__ float Wl[256 * 64];  // 64 KB
    int t = threadIdx.x;
    for (int i = t; i < 256 * 64; i += 256) Wl[i] = Wtp[i];
    __syncthreads();
    int d = t & 63, ln = t >> 6;
    float bp = biasp[d];
    const int ngroups = (N_NODES + 3) / 4;
    for (int g = blockIdx.x; g < ngroups; g += gridDim.x) {
        int n = g * 4 + ln;
        if (n < N_NODES) {
            float acc = bp;
#pragma unroll 4
            for (int k = 0; k < 256; k++) acc += h[(size_t)n * 256 + k] * Wl[k * 64 + d];
            xo[(size_t)n * 64 + d] = fmaxf(acc, 0.f);
        }
    }
}

// ---------------- graph pooling ----------------
__global__ __launch_bounds__(512) void pool2_kernel(const float* __restrict__ x,
                                                    float* __restrict__ rep) {
    int g = blockIdx.x;
    int t = threadIdx.x;
    int rp = t >> 6, d = t & 63;
    int start = (N_NODES * g + 63) >> 6;
    int end = (N_NODES * (g + 1) + 63) >> 6;
    float mx = -FLT_MAX, sm = 0.f;
    for (int r = start + rp; r < end; r += 8) {
        float v = x[(size_t)r * 64 + d];
        mx = fmaxf(mx, v); sm += v;
    }
    __shared__ float shm[8][64], shs[8][64];
    shm[rp][d] = mx; shs[rp][d] = sm;
    __syncthreads();
    if (rp == 0) {
#pragma unroll
        for (int i = 1; i < 8; i++) { mx = fmaxf(mx, shm[i][d]); sm += shs[i][d]; }
        rep[g * 128 + d] += mx;
        rep[g * 128 + 64 + d] += sm / (float)(end - start);
    }
}

// ---------------- fused MLP head: one block per graph ----------------
__global__ __launch_bounds__(256) void head_kernel(
    const float* __restrict__ rep,
    const float* __restrict__ W1, const float* __restrict__ b1,
    const float* __restrict__ W2, const float* __restrict__ b2,
    const float* __restrict__ W3, const float* __restrict__ b3,
    float* __restrict__ out) {
    int g = blockIdx.x, t = threadIdx.x;
    __shared__ float repL[128], o1sh[256], o2sh[128];
    if (t < 128) repL[t] = rep[g * 128 + t];
    __syncthreads();
    float a1 = b1[t];
    for (int k = 0; k < 128; k++) a1 += repL[k] * W1[k * 256 + t];
    o1sh[t] = fmaxf(a1, 0.f);
    __syncthreads();
    if (t < 128) {
        float a2 = b2[t];
        for (int k = 0; k < 256; k++) a2 += o1sh[k] * W2[k * 128 + t];
        o2sh[t] = fmaxf(a2, 0.f);
    }
    __syncthreads();
    if (t < 64) {
        float p = o2sh[t] * W3[t] + o2sh[t + 64] * W3[t + 64];
#pragma unroll
        for (int off = 32; off; off >>= 1) p += __shfl_xor(p, off);
        if (t == 0) out[g] = p + b3[0];
    }
}

extern "C" void kernel_launch(void* const* d_in, const int* in_sizes, int n_in,
                              void* d_out, int out_size, void* d_ws, size_t ws_size,
                              hipStream_t stream) {
    const float* x         = (const float*)d_in[0];
    const float* edge_attr = (const float*)d_in[1];
    const int*   ei        = (const int*)d_in[2];
    const float* Wq  = (const float*)d_in[4];
    const float* bq  = (const float*)d_in[5];
    const float* Wk  = (const float*)d_in[6];
    const float* bk  = (const float*)d_in[7];
    const float* Wv  = (const float*)d_in[8];
    const float* bv  = (const float*)d_in[9];
    const float* We  = (const float*)d_in[10];
    const float* Wsk = (const float*)d_in[11];
    const float* bsk = (const float*)d_in[12];
    const float* gam = (const float*)d_in[13];
    const float* bet = (const float*)d_in[14];
    const float* Wt  = (const float*)d_in[15];
    const float* bt  = (const float*)d_in[16];
    const float* W1  = (const float*)d_in[17];
    const float* b1  = (const float*)d_in[18];
    const float* W2  = (const float*)d_in[19];
    const float* b2  = (const float*)d_in[20];
    const float* W3  = (const float*)d_in[21];
    const float* b3  = (const float*)d_in[22];
    float* out = (float*)d_out;

    char* ws = (char*)d_ws;
    size_t off = 0;
    auto alloc = [&](size_t bytes) -> char* {
        char* p = ws + off;
        off += (bytes + 255) & ~(size_t)255;
        return p;
    };
    int*   rowptr = (int*)alloc((N_NODES + 1) * sizeof(int));
    int*   cur    = (int*)alloc(N_NODES * sizeof(int));
    int2*  epair  = (int2*)alloc((size_t)N_EDGES * sizeof(int2));
    float* qb     = (float*)alloc((size_t)N_NODES * 256 * sizeof(float));
    float* kvb    = (float*)alloc((size_t)N_NODES * 512 * sizeof(float));
    float* sbv    = (float*)alloc((size_t)N_NODES * 256 * sizeof(float));
    float* ub     = (float*)alloc((size_t)N_NODES * 256 * sizeof(float));
    float* hb     = (float*)alloc((size_t)N_NODES * 256 * sizeof(float));
    float* xb     = (float*)alloc((size_t)N_NODES * 64 * sizeof(float));
    float* stats  = (float*)alloc(512 * sizeof(float));
    float* Wtp    = (float*)alloc(256 * 64 * sizeof(float));
    float* biasp  = (float*)alloc(64 * sizeof(float));
    float* rep    = (float*)alloc(64 * 128 * sizeof(float));
    float* Wu     = (float*)alloc((size_t)NLAYER * 16384 * sizeof(float));
    float* bu     = (float*)alloc((size_t)NLAYER * 256 * sizeof(float));

    // CSR build
    hipMemsetAsync(cur, 0, N_NODES * sizeof(int), stream);
    count_kernel<<<(N_EDGES + 255) / 256, 256, 0, stream>>>(ei, cur);
    scan_kernel<<<1, 256, 0, stream>>>(cur, rowptr);
    hipMemsetAsync(cur, 0, N_NODES * sizeof(int), stream);
    fill_kernel<<<(N_EDGES + 255) / 256, 256, 0, stream>>>(ei, rowptr, cur, epair);

    hipMemsetAsync(rep, 0, 64 * 128 * sizeof(float), stream);
    wu_kernel<<<dim3(64, NLAYER), 256, 0, stream>>>(Wq, bq, We, Wu, bu);

    const float* xcur = x;
    for (int i = 0; i < NLAYER; i++) {
        node_lin_kernel<<<dim3((N_NODES + 63) / 64, 5), 256, 0, stream>>>(
            xcur,
            Wq + i * 16384, bq + i * 256,
            Wk + i * 16384, bk + i * 256,
            Wv + i * 16384, bv + i * 256,
            Wsk + i * 16384, bsk + i * 256,
            Wu + i * 16384, bu + i * 256,
            qb, kvb, sbv, ub);
        hipMemsetAsync(stats, 0, 512 * sizeof(float), stream);
        attn2_kernel<<<dim3(1024, 4), 256, 0, stream>>>(
            edge_attr, We + i * 16384, rowptr, epair, qb, kvb, ub, sbv, hb, stats);
        bn_fold_kernel<<<1, 256, 0, stream>>>(stats, gam + i * 256, bet + i * 256,
                                              Wt + i * 16384, bt + i * 64, Wtp, biasp);
        xform_kernel<<<2048, 256, 0, stream>>>(hb, Wtp, biasp, xb);
        pool2_kernel<<<64, 512, 0, stream>>>(xb, rep);
        xcur = xb;
    }

    head_kernel<<<64, 256, 0, stream>>>(rep, W1, b1, W2, b2, W3, b3, out);
}